// Round 8
// baseline (68.038 us; speedup 1.0000x reference)
//
#include <hip/hip_runtime.h>
#include <stdint.h>

typedef __bf16 bf16;
typedef __bf16 bf16x8 __attribute__((ext_vector_type(8)));
typedef float f32x4 __attribute__((ext_vector_type(4)));

#define LQn   2048
#define LKVn  1024
#define DM    512
#define NH    8

static __device__ __forceinline__ f32x4 mfma_bf16(bf16x8 a, bf16x8 b, f32x4 c) {
  return __builtin_amdgcn_mfma_f32_16x16x32_bf16(a, b, c, 0, 0, 0);
}

// ---------- weight transpose+convert: WT[mat][n][k] = (bf16)W[k][n], plain.
__global__ __launch_bounds__(256) void transpose_w_kernel(
    const float* __restrict__ Wq, const float* __restrict__ Wk,
    const float* __restrict__ Wv, const float* __restrict__ Wo,
    bf16* __restrict__ WT) {
  __shared__ float tile[64 * 65];
  const int bid = blockIdx.x;
  const int mat = bid >> 6;
  const int tb  = bid & 63;
  const int r0 = (tb >> 3) * 64;  // k block
  const int c0 = (tb & 7) * 64;   // n block
  const float* W = (mat == 0) ? Wq : (mat == 1) ? Wk : (mat == 2) ? Wv : Wo;
  const int t = threadIdx.x;
#pragma unroll
  for (int i = 0; i < 16; ++i) {
    int idx = i * 256 + t;
    int r = idx >> 6, c = idx & 63;
    tile[r * 65 + c] = W[(size_t)(r0 + r) * DM + c0 + c];
  }
  __syncthreads();
#pragma unroll
  for (int i = 0; i < 16; ++i) {
    int idx = i * 256 + t;
    int r = idx >> 6, c = idx & 63;   // out row n=c0+r, col k=r0+c
    WT[(size_t)mat * DM * DM + (size_t)(c0 + r) * DM + r0 + c] =
        (bf16)tile[c * 65 + r];
  }
}

// ---------- projection panel: LDS-free, barrier-free.
// Block = 128 rows x 128 cols; wave w owns rows [m0+w*32, +32), all 4 waves
// share cols [n0, n0+128) -> B-fragments L1-reused across waves.
// A fp32 read once (32B/lane contiguous), split to bf16 hi/lo in regs.
// B from L2-resident WT[n][k] bf16 (16B/lane contiguous; full 64B lines/wave).
// Register double-buffered prefetch; MFMA order identical to prior rounds.
template <bool SPLIT>
__device__ __forceinline__ void proj_panel(const float* __restrict__ A,
                                           const bf16* __restrict__ WTm,
                                           bf16* __restrict__ Chi,
                                           bf16* __restrict__ Clo,
                                           int m0, int n0) {
  const int t = threadIdx.x;
  const int lane = t & 63;
  const int w = t >> 6;            // 0..3
  const int ln = lane & 15, hi4 = lane >> 4;
  const int mrow = m0 + w * 32;    // wave's 32 rows
  const f32x4 zf = {0.f, 0.f, 0.f, 0.f};
  f32x4 acc[2][8];
#pragma unroll
  for (int a = 0; a < 2; ++a)
#pragma unroll
    for (int b = 0; b < 8; ++b) acc[a][b] = zf;

  const float* gA = A + (size_t)(mrow + ln) * 512 + hi4 * 8;
  const bf16*  gB = WTm + (size_t)(n0 + ln) * 512 + hi4 * 8;

  bf16x8 ahA[2], alA[2], bA[8], ahB[2], alB[2], bB[8];

  auto LD = [&](int ks, bf16x8* ah, bf16x8* al, bf16x8* bv) {
#pragma unroll
    for (int mf = 0; mf < 2; ++mf) {
      const float* g = gA + (size_t)mf * 16 * 512 + ks * 32;
      f32x4 x0 = *(const f32x4*)g, x1 = *(const f32x4*)(g + 4);
      bf16x8 hv, lv;
#pragma unroll
      for (int e = 0; e < 4; ++e) {
        float x = x0[e]; bf16 hh = (bf16)x; hv[e] = hh;
        float y = x1[e]; bf16 h2 = (bf16)y; hv[4 + e] = h2;
        if constexpr (SPLIT) { lv[e] = (bf16)(x - (float)hh); lv[4 + e] = (bf16)(y - (float)h2); }
      }
      ah[mf] = hv; al[mf] = lv;
    }
#pragma unroll
    for (int nf = 0; nf < 8; ++nf)
      bv[nf] = *(const bf16x8*)(gB + (size_t)nf * 16 * 512 + ks * 32);
  };
  auto FM = [&](bf16x8* ah, bf16x8* al, bf16x8* bv) {
#pragma unroll
    for (int mf = 0; mf < 2; ++mf)
#pragma unroll
      for (int nf = 0; nf < 8; ++nf) {
        acc[mf][nf] = mfma_bf16(ah[mf], bv[nf], acc[mf][nf]);
        if constexpr (SPLIT) acc[mf][nf] = mfma_bf16(al[mf], bv[nf], acc[mf][nf]);
      }
  };

  LD(0, ahA, alA, bA);
#pragma unroll
  for (int ks = 0; ks < 16; ks += 2) {
    LD(ks + 1, ahB, alB, bB);
    FM(ahA, alA, bA);
    if (ks + 2 < 16) LD(ks + 2, ahA, alA, bA);
    FM(ahB, alB, bB);
  }

#pragma unroll
  for (int mf = 0; mf < 2; ++mf)
#pragma unroll
    for (int nf = 0; nf < 8; ++nf)
#pragma unroll
      for (int e = 0; e < 4; ++e) {
        size_t off = (size_t)(mrow + mf * 16 + hi4 * 4 + e) * 512 +
                     n0 + nf * 16 + ln;
        float x = acc[mf][nf][e];
        bf16 h = (bf16)x;
        Chi[off] = h;
        if constexpr (SPLIT) Clo[off] = (bf16)(x - (float)h);
      }
}

// 256 blocks x 256 thr: q 128 (32m x 4n), k 64 (16m x 4n), v 64.
__global__ __launch_bounds__(256) void proj_kernel(
    const float* __restrict__ q, const float* __restrict__ k,
    const float* __restrict__ v, const bf16* __restrict__ WT,
    bf16* __restrict__ Qhi, bf16* __restrict__ Qlo,
    bf16* __restrict__ Khi, bf16* __restrict__ Klo, bf16* __restrict__ Vb) {
  const int bid = blockIdx.x;
  if (bid < 128) {
    int m0 = (bid >> 2) * 128, n0 = (bid & 3) * 128;
    proj_panel<true>(q, WT, Qhi, Qlo, m0, n0);
  } else if (bid < 192) {
    int b2 = bid - 128;
    int m0 = (b2 >> 2) * 128, n0 = (b2 & 3) * 128;
    proj_panel<true>(k, WT + (size_t)DM * DM, Khi, Klo, m0, n0);
  } else {
    int b2 = bid - 192;
    int m0 = (b2 >> 2) * 128, n0 = (b2 & 3) * 128;
    proj_panel<false>(v, WT + (size_t)2 * DM * DM, Vb, nullptr, m0, n0);
  }
}

// ---------- output projection: LDS-free, barrier-free, reg-pipelined.
// Block = 64 rows x 128 cols; wave w owns rows [m0+w*16, +16), shared cols.
__global__ __launch_bounds__(256) void outproj_kernel(
    const bf16* __restrict__ AO, const bf16* __restrict__ WoT,
    float* __restrict__ out) {
  const int bid = blockIdx.x;
  const int m0 = (bid >> 2) * 64, n0 = (bid & 3) * 128;
  const int t = threadIdx.x;
  const int lane = t & 63;
  const int w = t >> 6;
  const int ln = lane & 15, hi4 = lane >> 4;
  const int mrow = m0 + w * 16;
  const f32x4 zf = {0.f, 0.f, 0.f, 0.f};
  f32x4 acc[8];
#pragma unroll
  for (int b = 0; b < 8; ++b) acc[b] = zf;

  const bf16* gA = AO + (size_t)(mrow + ln) * 512 + hi4 * 8;
  const bf16* gB = WoT + (size_t)(n0 + ln) * 512 + hi4 * 8;

  bf16x8 aA, bAv[8], aB, bBv[8];
  auto LD = [&](int ks, bf16x8& av, bf16x8* bv) {
    av = *(const bf16x8*)(gA + ks * 32);
#pragma unroll
    for (int nf = 0; nf < 8; ++nf)
      bv[nf] = *(const bf16x8*)(gB + (size_t)nf * 16 * 512 + ks * 32);
  };
  auto FM = [&](bf16x8& av, bf16x8* bv) {
#pragma unroll
    for (int nf = 0; nf < 8; ++nf) acc[nf] = mfma_bf16(av, bv[nf], acc[nf]);
  };

  LD(0, aA, bAv);
#pragma unroll
  for (int ks = 0; ks < 16; ks += 2) {
    LD(ks + 1, aB, bBv);
    FM(aA, bAv);
    if (ks + 2 < 16) LD(ks + 2, aA, bAv);
    FM(aB, bBv);
  }

#pragma unroll
  for (int nf = 0; nf < 8; ++nf)
#pragma unroll
    for (int e = 0; e < 4; ++e)
      out[(size_t)(mrow + hi4 * 4 + e) * 512 + n0 + nf * 16 + ln] = acc[nf][e];
}

// ---------- banded attention: verbatim proven version (reads plain Q/K/V).
__global__ __launch_bounds__(512, 2) void attn_kernel(
    const bf16* __restrict__ Qhi, const bf16* __restrict__ Qlo,
    const bf16* __restrict__ Khi, const bf16* __restrict__ Klo,
    const bf16* __restrict__ Vb, bf16* __restrict__ AO) {
  __shared__ bf16 smQh[128 * 64];
  __shared__ bf16 smQl[128 * 64];
  __shared__ bf16 smKh[128 * 64];
  __shared__ bf16 smKl[128 * 64];
  __shared__ bf16 smVt[64 * 128];   // [d][p], swizzled
  __shared__ bf16 smP[128 * 128];   // swizzled
  const int bid = blockIdx.x;
  const int qt = bid & 15;
  const int h  = (bid >> 4) & 7;
  const int b  = bid >> 7;
  const int j0 = qt * 128;
  const int pbase = (j0 >> 1) - 63;  // KV rows pbase..pbase+127
  const int t = threadIdx.x;
  const int lane = t & 63, w = t >> 6;   // 8 waves, 16 q-rows each
  const int ln = lane & 15, hi4 = lane >> 4;

  // stage Q,K (hi/lo, swizzled [128][64]) and V transposed ([64][128])
#pragma unroll
  for (int i = 0; i < 2; ++i) {
    int idx = i * 512 + t;          // 1024 units
    int r = idx >> 3, u = idx & 7;
    int sw = r * 64 + ((u ^ (r & 7)) * 8);
    size_t qoff = ((size_t)(b * LQn + j0 + r)) * 512 + h * 64 + u * 8;
    *(bf16x8*)&smQh[sw] = *(const bf16x8*)(Qhi + qoff);
    *(bf16x8*)&smQl[sw] = *(const bf16x8*)(Qlo + qoff);
    int p = pbase + r;
    p = p < 0 ? 0 : (p > LKVn - 1 ? LKVn - 1 : p);  // clamped rows masked later
    size_t koff = ((size_t)(b * LKVn + p)) * 512 + h * 64 + u * 8;
    *(bf16x8*)&smKh[sw] = *(const bf16x8*)(Khi + koff);
    *(bf16x8*)&smKl[sw] = *(const bf16x8*)(Klo + koff);
    bf16x8 vv = *(const bf16x8*)(Vb + koff);
#pragma unroll
    for (int e = 0; e < 8; ++e) {
      int rv = u * 8 + e;           // d-row of smVt
      smVt[rv * 128 + (((r >> 3) ^ (rv & 15)) * 8) + (r & 7)] = vv[e];
    }
  }
  __syncthreads();

  // S = Q K^T  (this wave: q-rows w*16..w*16+15, all 128 kv cols), 3-term
  const f32x4 zf = {0.f, 0.f, 0.f, 0.f};
  f32x4 s[8];
#pragma unroll
  for (int cf = 0; cf < 8; ++cf) s[cf] = zf;
#pragma unroll
  for (int kk = 0; kk < 64; kk += 32) {
    const int ub = kk >> 3;
    int addrq = (w * 16 + ln) * 64 + (((ub + hi4) ^ (ln & 7)) * 8);
    bf16x8 ah = *(const bf16x8*)&smQh[addrq];
    bf16x8 al = *(const bf16x8*)&smQl[addrq];
#pragma unroll
    for (int cf = 0; cf < 8; ++cf) {
      int addrk = (cf * 16 + ln) * 64 + (((ub + hi4) ^ (ln & 7)) * 8);
      bf16x8 bh = *(const bf16x8*)&smKh[addrk];
      bf16x8 bl = *(const bf16x8*)&smKl[addrk];
      s[cf] = mfma_bf16(ah, bh, s[cf]);
      s[cf] = mfma_bf16(ah, bl, s[cf]);
      s[cf] = mfma_bf16(al, bh, s[cf]);
    }
  }

  // mask (band + left clamp), wave-parallel softmax, P -> bf16 LDS (swizzled)
#pragma unroll
  for (int r = 0; r < 4; ++r) {
    int rloc = w * 16 + hi4 * 4 + r;
    int wlo = rloc >> 1;
    int colmin = wlo > -pbase ? wlo : -pbase;
    int colmax = wlo + 63;
    float sv[8];
    float mx = -1e30f;
#pragma unroll
    for (int cf = 0; cf < 8; ++cf) {
      int col = cf * 16 + ln;
      float val = s[cf][r];
      bool ok = (col >= colmin) && (col <= colmax);
      sv[cf] = ok ? val : -1e30f;
      mx = fmaxf(mx, sv[cf]);
    }
#pragma unroll
    for (int msk = 1; msk < 16; msk <<= 1) mx = fmaxf(mx, __shfl_xor(mx, msk, 64));
    float sum = 0.f;
#pragma unroll
    for (int cf = 0; cf < 8; ++cf) {
      sv[cf] = __expf(sv[cf] - mx);
      sum += sv[cf];
    }
#pragma unroll
    for (int msk = 1; msk < 16; msk <<= 1) sum += __shfl_xor(sum, msk, 64);
    float rs = 1.0f / sum;
#pragma unroll
    for (int cf = 0; cf < 8; ++cf) {
      int uu = cf * 2 + (ln >> 3);
      smP[rloc * 128 + ((uu ^ (rloc & 15)) * 8) + (ln & 7)] = (bf16)(sv[cf] * rs);
    }
  }
  __syncthreads();

  // O = P @ V   (wave's 16 q-rows x 64 d)
  f32x4 o[4];
#pragma unroll
  for (int nf = 0; nf < 4; ++nf) o[nf] = zf;
#pragma unroll
  for (int kk = 0; kk < 128; kk += 32) {
    const int ub = kk >> 3;
    bf16x8 pa = *(const bf16x8*)&smP[(w * 16 + ln) * 128 + (((ub + hi4) ^ ln) * 8)];
#pragma unroll
    for (int nf = 0; nf < 4; ++nf) {
      int d = nf * 16 + ln;
      bf16x8 vf = *(const bf16x8*)&smVt[d * 128 + (((ub + hi4) ^ ln) * 8)];
      o[nf] = mfma_bf16(pa, vf, o[nf]);
    }
  }

  // write AO[b, j0+rloc, h*64 + d] (plain row-major)
#pragma unroll
  for (int nf = 0; nf < 4; ++nf)
#pragma unroll
    for (int e = 0; e < 4; ++e) {
      int rloc = w * 16 + hi4 * 4 + e;
      AO[((size_t)(b * LQn + j0 + rloc)) * 512 + h * 64 + nf * 16 + ln] =
          (bf16)o[nf][e];
    }
}

extern "C" void kernel_launch(void* const* d_in, const int* in_sizes, int n_in,
                              void* d_out, int out_size, void* d_ws, size_t ws_size,
                              hipStream_t stream) {
  const float* q    = (const float*)d_in[0];
  const float* k    = (const float*)d_in[1];
  const float* v    = (const float*)d_in[2];
  const float* Wq   = (const float*)d_in[3];
  const float* Wk   = (const float*)d_in[4];
  const float* Wv   = (const float*)d_in[5];
  const float* Wout = (const float*)d_in[6];
  float* out = (float*)d_out;

  char* ws = (char*)d_ws;
  bf16* WT   = (bf16*)ws;                          // 4*512*512*2 = 2 MB
  bf16* Qhi  = (bf16*)(ws + (size_t)(2  << 20));   // 4 MB
  bf16* Qlo  = (bf16*)(ws + (size_t)(6  << 20));   // 4 MB
  bf16* Khi  = (bf16*)(ws + (size_t)(10 << 20));   // 2 MB
  bf16* Klo  = (bf16*)(ws + (size_t)(12 << 20));   // 2 MB
  bf16* Vbuf = (bf16*)(ws + (size_t)(14 << 20));   // 2 MB
  bf16* AO   = (bf16*)(ws + (size_t)(16 << 20));   // 4 MB  (total 20 MB)

  transpose_w_kernel<<<256, 256, 0, stream>>>(Wq, Wk, Wv, Wout, WT);
  proj_kernel<<<256, 256, 0, stream>>>(q, k, v, WT, Qhi, Qlo, Khi, Klo, Vbuf);
  attn_kernel<<<256, 512, 0, stream>>>(Qhi, Qlo, Khi, Klo, Vbuf, AO);
  outproj_kernel<<<256, 256, 0, stream>>>(AO, WT + (size_t)3 * DM * DM, out);
}